// Round 4
// baseline (269.157 us; speedup 1.0000x reference)
//
#include <hip/hip_runtime.h>
#include <cmath>

#define DEVI __device__ __forceinline__

DEVI float sigm(float x){ return 1.f/(1.f+expf(-x)); }

typedef __attribute__((ext_vector_type(8))) _Float16 half8;
typedef __attribute__((ext_vector_type(4))) _Float16 half4;
typedef __attribute__((ext_vector_type(4))) float float4v;

// ---------------- utility ----------------

__global__ void k_zero(float* __restrict__ p, int n){
  int i = blockIdx.x*256 + threadIdx.x;
  if (i < n) p[i] = 0.f;
}

// merged independent input-stage kernel:
//   blocks [0,32):    mem column sums (atomic cm) + row-L2-normalized fp16 copy
//   blocks [32,160):  link row sums + col sums (128 blocks x 16 rows, 4-row groups)
//   blocks [160,672): allocation weighting, ONE n PER WAVE (no barriers, no Sa atomic)
__global__ __launch_bounds__(256) void k_stage1(
    const float* __restrict__ mem, float* __restrict__ cm, _Float16* __restrict__ mem_h,
    const float* __restrict__ usage, float* __restrict__ alloc,
    const float* __restrict__ link, float* __restrict__ rsl, float* __restrict__ csl)
{
  __shared__ float smem[4][132];
  const int blk = blockIdx.x, t = threadIdx.x;
  const int wv = t >> 6, lane = t & 63;

  if (blk < 32){
    // ---- prep_mem ----
    int n0 = blk*64;
    float c0 = 0.f, c1 = 0.f;
    for (int r = wv; r < 64; r += 4){
      const float* a = mem + (size_t)(n0+r)*128;
      float x0 = a[lane], x1 = a[lane+64];
      float ss = x0*x0 + x1*x1;
      #pragma unroll
      for (int o = 1; o < 64; o <<= 1) ss += __shfl_xor(ss, o);
      float invn = 1.f / fmaxf(sqrtf(ss), 1e-12f);
      mem_h[(size_t)(n0+r)*128 + lane]      = (_Float16)(x0*invn);
      mem_h[(size_t)(n0+r)*128 + 64 + lane] = (_Float16)(x1*invn);
      c0 += x0; c1 += x1;
    }
    smem[wv][lane] = c0; smem[wv][64+lane] = c1;
    __syncthreads();
    if (t < 128) atomicAdd(&cm[t], smem[0][t]+smem[1][t]+smem[2][t]+smem[3][t]);
  } else if (blk < 160){
    // ---- link row+col sums, 16 rows per block, 4-row groups (8 loads in flight) ----
    int r0 = (blk - 32)*16;
    int c0 = t*8;
    float colacc[8];
    #pragma unroll
    for (int j = 0; j < 8; j++) colacc[j] = 0.f;
    for (int rg = 0; rg < 16; rg += 4){
      float4v v0[4], v1[4];
      #pragma unroll
      for (int u = 0; u < 4; u++){
        const float* lp = link + (size_t)(r0+rg+u)*2048 + c0;
        v0[u] = *(const float4v*)lp;
        v1[u] = *(const float4v*)(lp+4);
      }
      #pragma unroll
      for (int u = 0; u < 4; u++){
        float s = 0.f;
        #pragma unroll
        for (int j = 0; j < 4; j++){
          colacc[j]   += v0[u][j]; colacc[4+j] += v1[u][j];
          s += v0[u][j] + v1[u][j];
        }
        #pragma unroll
        for (int o = 32; o > 0; o >>= 1) s += __shfl_xor(s, o);
        if (lane == 0) smem[wv][rg+u] = s;
      }
    }
    __syncthreads();
    if (t < 16) rsl[r0+t] = smem[0][t]+smem[1][t]+smem[2][t]+smem[3][t];
    #pragma unroll
    for (int j = 0; j < 8; j++) atomicAdd(&csl[c0+j], colacc[j]);
  } else {
    // ---- alloc: one n per wave, 4 waves/block, 512 blocks ----
    int n = (blk - 160)*4 + wv;
    float un = usage[n];
    float prod = 1.f;
    #pragma unroll
    for (int i = 0; i < 32; i++){
      int m = lane + i*64;
      float um = usage[m];
      bool before = (um < un) || (um == un && m < n);
      prod *= before ? (1.f - um) : 1.f;
    }
    #pragma unroll
    for (int o = 32; o > 0; o >>= 1) prod *= __shfl_xor(prod, o);
    if (lane == 0) alloc[n] = un * prod;
  }
}

// cin_h[b,k] = fp16( k<1024 ? x[b,k] : cm[(k-1024)%128]/2048 )
__global__ void k_cin(const float* __restrict__ x, const float* __restrict__ cm, _Float16* __restrict__ cin){
  int idx = blockIdx.x*256 + threadIdx.x;     // 256*1536
  int b = idx / 1536, k = idx - b*1536;
  float v = (k < 1024) ? x[b*1024 + k] : cm[(k-1024) & 127] * (1.f/2048.f);
  cin[idx] = (_Float16)v;
}

// LSTM gate activation -> fp16 h
__global__ void k_lstm(const float* __restrict__ g, _Float16* __restrict__ h){
  int idx = blockIdx.x*256 + threadIdx.x;    // 256*1024
  int b = idx >> 10, j = idx & 1023;
  const float* gr = g + (size_t)b*4096;
  float c = sigm(gr[j]) * tanhf(gr[2048 + j]);
  h[idx] = (_Float16)(sigm(gr[3072 + j]) * tanhf(c));
}

// ---------------- fp16 MFMA NT GEMM: C = A @ B^T + bias1 + bias2 ----------------
// A is fp16. B is fp16 or fp32; fp32 is loaded RAW into registers and converted
// only at the LDS-write point (after the MFMA section) so the vmcnt wait does not
// land in front of the compute.
#define QA 264
#define QB 520

template<typename TB> struct BReg;
template<> struct BReg<_Float16>{
  half8 v;
  DEVI void load(const _Float16* p){ v = *(const half8*)p; }
  DEVI half8 get() const { return v; }
};
template<> struct BReg<float>{
  float4v a, b;
  DEVI void load(const float* p){ a = *(const float4v*)p; b = *(const float4v*)(p+4); }
  DEVI half8 get() const {
    half8 h;
    #pragma unroll
    for (int j = 0; j < 4; j++){ h[j] = (_Float16)a[j]; h[4+j] = (_Float16)b[j]; }
    return h;
  }
};

template<typename TB>
__global__ __launch_bounds__(256) void gemm_t(
    const _Float16* __restrict__ A, const TB* __restrict__ Bm, float* __restrict__ C,
    int M, int N, int K,
    const float* __restrict__ bias1, const float* __restrict__ bias2)
{
  __shared__ _Float16 Ah[2][8*QA];
  __shared__ _Float16 Bh[2][8*QB];
  const int tid = threadIdx.x;
  const int m0 = blockIdx.y*32, n0 = blockIdx.x*64;
  const int T = K >> 6;
  const int arow = tid >> 3, aq = tid & 7;
  const int brow = tid >> 3, bq = tid & 7;
  int nB0 = n0 + brow;      if (nB0 >= N) nB0 = N - 1;
  int nB1 = n0 + brow + 32; if (nB1 >= N) nB1 = N - 1;
  const _Float16* Aptr = A + (size_t)(m0 + arow)*K + aq*8;
  const TB* Bp0 = Bm + (size_t)nB0*K + bq*8;
  const TB* Bp1 = Bm + (size_t)nB1*K + bq*8;
  const int wA  = aq*QA + arow*8;
  const int wB0 = bq*QB + brow*8;
  const int wB1 = bq*QB + (brow+32)*8;
  const int wv_ = tid >> 6, lane = tid & 63;
  const int fq = lane >> 4, fr = lane & 15;
  const int m16 = (wv_ & 1)*16, nb = (wv_ >> 1)*32;

  half8 ra;
  BReg<TB> rb0, rb1;
  ra = *(const half8*)(Aptr);
  rb0.load(Bp0);
  rb1.load(Bp1);
  *(half8*)&Ah[0][wA]  = ra;
  *(half8*)&Bh[0][wB0] = rb0.get();
  *(half8*)&Bh[0][wB1] = rb1.get();
  __syncthreads();

  float4v acc0 = {0.f,0.f,0.f,0.f}, acc1 = {0.f,0.f,0.f,0.f};
  for (int t = 0; t < T; t++){
    const int cur = t & 1, nxt = cur ^ 1;
    if (t+1 < T){
      ra = *(const half8*)(Aptr + (t+1)*64);
      rb0.load(Bp0 + (t+1)*64);
      rb1.load(Bp1 + (t+1)*64);
    }
    #pragma unroll
    for (int s = 0; s < 2; s++){
      int q = s*4 + fq;
      half8 a  = *(half8*)&Ah[cur][q*QA + (m16+fr)*8];
      half8 b0 = *(half8*)&Bh[cur][q*QB + (nb+fr)*8];
      half8 b1 = *(half8*)&Bh[cur][q*QB + (nb+16+fr)*8];
      acc0 = __builtin_amdgcn_mfma_f32_16x16x32_f16(a, b0, acc0, 0, 0, 0);
      acc1 = __builtin_amdgcn_mfma_f32_16x16x32_f16(a, b1, acc1, 0, 0, 0);
    }
    if (t+1 < T){
      *(half8*)&Ah[nxt][wA]  = ra;
      *(half8*)&Bh[nxt][wB0] = rb0.get();   // cvt happens here, after the MFMAs
      *(half8*)&Bh[nxt][wB1] = rb1.get();
    }
    __syncthreads();
  }

  const int colA = n0 + nb + fr, colB = colA + 16;
  #pragma unroll
  for (int i = 0; i < 4; i++){
    int m = m0 + m16 + fq*4 + i;
    if (colA < N){
      float v = acc0[i];
      if (bias1) v += bias1[colA];
      if (bias2) v += bias2[colA];
      C[(size_t)m*N + colA] = v;
    }
    if (colB < N){
      float v = acc1[i];
      if (bias1) v += bias1[colB];
      if (bias2) v += bias2[colB];
      C[(size_t)m*N + colB] = v;
    }
  }
}

DEVI float blockReduce128(float v, float* lds2){
  #pragma unroll
  for (int o = 32; o > 0; o >>= 1) v += __shfl_xor(v, o);
  int w = threadIdx.x >> 6;
  __syncthreads();
  if ((threadIdx.x & 63) == 0) lds2[w] = v;
  __syncthreads();
  return lds2[0] + lds2[1];
}

// parse itf; wv_h has invwv folded, rks_h has invk*str folded
__global__ __launch_bounds__(128) void k_parse(const float* __restrict__ itf,
    _Float16* __restrict__ wv_h, float* __restrict__ ev, float* __restrict__ av,
    float* __restrict__ wg_, float* __restrict__ ag_,
    float* __restrict__ rm0, float* __restrict__ rm1, float* __restrict__ rm2,
    _Float16* __restrict__ rks_h)
{
  __shared__ float red[2];
  int b = blockIdx.x, t = threadIdx.x;
  const float* it = itf + (size_t)b*787;
  float wg = sigm(it[256]);
  float ag = sigm(it[257]);
  if (t == 0){ wg_[b] = wg; ag_[b] = ag; }
  float w = it[t];
  av[b*128 + t] = w * wg;
  ev[b*128 + t] = sigm(it[128 + t]) * wg;
  float ss = blockReduce128(w*w, red);
  float invwv = 1.f / fmaxf(sqrtf(ss), 1e-12f);
  wv_h[b*128 + t] = (_Float16)(w * invwv);
  if (t < 4){
    int rr = t;
    float m0v = it[259 + rr*3 + 0], m1v = it[259 + rr*3 + 1], m2v = it[259 + rr*3 + 2];
    float mx = fmaxf(m0v, fmaxf(m1v, m2v));
    float e0 = expf(m0v - mx), e1 = expf(m1v - mx), e2 = expf(m2v - mx);
    float inv = 1.f / (e0 + e1 + e2);
    rm0[b*4 + rr] = e0*inv; rm1[b*4 + rr] = e1*inv; rm2[b*4 + rr] = e2*inv;
  }
  #pragma unroll
  for (int rr = 0; rr < 4; rr++){
    float kv = it[275 + rr*128 + t];
    float ks = blockReduce128(kv*kv, red);
    float sx = it[271 + rr];
    float str = fmaxf(sx, 0.f) + log1pf(expf(-fabsf(sx)));
    float invk = 1.f / fmaxf(sqrtf(ks), 1e-12f);
    rks_h[((size_t)b*4 + rr)*128 + t] = (_Float16)(kv * invk * str);
  }
}

// softmax over 2048-wide rows, fused write-weighting epilogue
__global__ __launch_bounds__(256) void k_softmax_ww(float* __restrict__ P,
    const float* __restrict__ alloc, const float* __restrict__ wg, const float* __restrict__ ag){
  __shared__ float red[4];
  float* p = P + (size_t)blockIdx.x*2048;
  int t = threadIdx.x;
  float r[8];
  float mx = -3.4e38f;
  #pragma unroll
  for (int i = 0; i < 8; i++){ r[i] = p[t + i*256]; mx = fmaxf(mx, r[i]); }
  #pragma unroll
  for (int o = 32; o > 0; o >>= 1) mx = fmaxf(mx, __shfl_xor(mx, o));
  if ((t & 63) == 0) red[t >> 6] = mx;
  __syncthreads();
  mx = fmaxf(fmaxf(red[0], red[1]), fmaxf(red[2], red[3]));
  float s = 0.f;
  #pragma unroll
  for (int i = 0; i < 8; i++){ r[i] = expf(r[i] - mx); s += r[i]; }
  #pragma unroll
  for (int o = 32; o > 0; o >>= 1) s += __shfl_xor(s, o);
  __syncthreads();
  if ((t & 63) == 0) red[t >> 6] = s;
  __syncthreads();
  s = red[0] + red[1] + red[2] + red[3];
  float inv = 1.f / s;
  float wgb = wg[blockIdx.x], agb = ag[blockIdx.x];
  #pragma unroll
  for (int i = 0; i < 8; i++){
    int col = t + i*256;
    p[col] = wgb*(0.5f*r[i]*inv + 0.5f*alloc[col]*agb);
  }
}

// bw/fw from link sums + lu sums; Salloc reduced per-block from alloc (no global atomic);
// tb analytic: tb[b] = wg[b]*(0.5 + 0.5*ag[b]*Salloc)
__global__ __launch_bounds__(256) void k_bwfw(const float* __restrict__ ww,
                       const float* __restrict__ wg, const float* __restrict__ ag,
                       const float* __restrict__ alloc,
                       const float* __restrict__ rowsum, const float* __restrict__ colsum,
                       float* __restrict__ bw, float* __restrict__ fw){
  __shared__ float sq[4][64], sd[4][64];
  __shared__ float sred[4];
  __shared__ float tbs[256];
  int t = threadIdx.x & 63, z = threadIdx.x >> 6;
  int m = blockIdx.x*64 + t;
  // Salloc: redundant per-block tree reduce over alloc[0..2048)
  float sa = 0.f;
  #pragma unroll
  for (int i = 0; i < 8; i++) sa += alloc[threadIdx.x + i*256];
  #pragma unroll
  for (int o = 32; o > 0; o >>= 1) sa += __shfl_xor(sa, o);
  if (t == 0) sred[z] = sa;
  __syncthreads();
  sa = (sred[0]+sred[1]) + (sred[2]+sred[3]);
  tbs[threadIdx.x] = wg[threadIdx.x]*(0.5f + 0.5f*ag[threadIdx.x]*sa);
  __syncthreads();
  float q = 0.f, dd = 0.f;
  for (int b = z*64; b < z*64 + 64; b += 4){
    float w0 = ww[(size_t)(b+0)*2048 + m];
    float w1 = ww[(size_t)(b+1)*2048 + m];
    float w2 = ww[(size_t)(b+2)*2048 + m];
    float w3 = ww[(size_t)(b+3)*2048 + m];
    q  = fmaf(tbs[b+0], w0, q);  dd = fmaf(w0, w0, dd);
    q  = fmaf(tbs[b+1], w1, q);  dd = fmaf(w1, w1, dd);
    q  = fmaf(tbs[b+2], w2, q);  dd = fmaf(w2, w2, dd);
    q  = fmaf(tbs[b+3], w3, q);  dd = fmaf(w3, w3, dd);
  }
  sq[z][t] = q; sd[z][t] = dd;
  __syncthreads();
  if (z == 0){
    q  = sq[0][t] + sq[1][t] + sq[2][t] + sq[3][t];
    dd = sd[0][t] + sd[1][t] + sd[2][t] + sd[3][t];
    float lus = (q - dd) * (1.f/256.f);
    bw[m] = (0.9f*colsum[m] + 0.1f*lus) * (1.f/2048.f);
    fw[m] = (0.9f*rowsum[m] + 0.1f*lus) * (1.f/2048.f);
  }
}

// fused memory update: memn = mem*(1-ww^T@ev/B)+ww^T@av/B, emit fp16 normalized
// (memn_h) + fp16 raw TRANSPOSED (memnT_h), and bwm/fwm partials (atomic, pre-zeroed).
__global__ __launch_bounds__(256) void k_memupdate_fused(const float* __restrict__ ww,
    const float* __restrict__ ev, const float* __restrict__ av,
    const float* __restrict__ mem, const float* __restrict__ bw, const float* __restrict__ fw,
    _Float16* __restrict__ memn_h, _Float16* __restrict__ memnT_h,
    float* __restrict__ bwm, float* __restrict__ fwm)
{
  __shared__ float Ws[16][34];
  __shared__ float Es[16][132], Vs[16][132];
  __shared__ float lb[128], lf[128];
  __shared__ _Float16 Traw[32][132];
  const int n0 = blockIdx.x*32;
  const int tid = threadIdx.x, tx = tid & 31, ty = tid >> 5;
  if (tid < 128){ lb[tid] = 0.f; lf[tid] = 0.f; }
  const int wk = tid >> 4, wn = (tid & 15)*2;
  const int ek = tid >> 4, ec = (tid & 15)*8;
  float ae[4][4] = {}, aa[4][4] = {};
  for (int k0 = 0; k0 < 256; k0 += 16){
    float2 vw  = *(const float2*)(ww + (size_t)(k0+wk)*2048 + n0 + wn);
    float4 ve0 = *(const float4*)(ev + (size_t)(k0+ek)*128 + ec);
    float4 ve1 = *(const float4*)(ev + (size_t)(k0+ek)*128 + ec + 4);
    float4 va0 = *(const float4*)(av + (size_t)(k0+ek)*128 + ec);
    float4 va1 = *(const float4*)(av + (size_t)(k0+ek)*128 + ec + 4);
    __syncthreads();
    Ws[wk][wn] = vw.x; Ws[wk][wn+1] = vw.y;
    *(float4*)&Es[ek][ec] = ve0; *(float4*)&Es[ek][ec+4] = ve1;
    *(float4*)&Vs[ek][ec] = va0; *(float4*)&Vs[ek][ec+4] = va1;
    __syncthreads();
    #pragma unroll
    for (int k = 0; k < 16; k++){
      float a[4], e[4], v[4];
      #pragma unroll
      for (int i = 0; i < 4; i++) a[i] = Ws[k][ty*4+i];
      #pragma unroll
      for (int j = 0; j < 4; j++){ e[j] = Es[k][tx*4+j]; v[j] = Vs[k][tx*4+j]; }
      #pragma unroll
      for (int i = 0; i < 4; i++)
        #pragma unroll
        for (int j = 0; j < 4; j++){
          ae[i][j] = fmaf(a[i], e[j], ae[i][j]);
          aa[i][j] = fmaf(a[i], v[j], aa[i][j]);
        }
    }
  }
  float ab[4] = {0,0,0,0}, af[4] = {0,0,0,0};
  #pragma unroll
  for (int i = 0; i < 4; i++){
    int n = n0 + ty*4 + i;
    float bwn = bw[n], fwn = fw[n];
    float v[4]; float ss = 0.f;
    #pragma unroll
    for (int j = 0; j < 4; j++){
      int d = tx*4 + j;
      float em = ae[i][j]*(1.f/256.f), am = aa[i][j]*(1.f/256.f);
      float mv = mem[(size_t)n*128 + d]*(1.f - em) + am;
      v[j] = mv; ss += mv*mv;
      ab[j] = fmaf(bwn, mv, ab[j]);
      af[j] = fmaf(fwn, mv, af[j]);
    }
    #pragma unroll
    for (int o = 1; o < 32; o <<= 1) ss += __shfl_xor(ss, o);
    float invn = 1.f / fmaxf(sqrtf(ss), 1e-12f);
    half4 hn, hr;
    #pragma unroll
    for (int j = 0; j < 4; j++){ hn[j] = (_Float16)(v[j]*invn); hr[j] = (_Float16)v[j]; }
    *(half4*)(memn_h + (size_t)n*128 + tx*4) = hn;
    *(half4*)&Traw[ty*4+i][tx*4] = hr;
  }
  __syncthreads();
  // transposed emit: thread -> (d, 16-col segment)
  {
    int d = tid >> 1, seg = (tid & 1)*16;
    half8 o0, o1;
    #pragma unroll
    for (int j = 0; j < 8; j++){ o0[j] = Traw[seg+j][d]; o1[j] = Traw[seg+8+j][d]; }
    *(half8*)(memnT_h + (size_t)d*2048 + n0 + seg)     = o0;
    *(half8*)(memnT_h + (size_t)d*2048 + n0 + seg + 8) = o1;
  }
  #pragma unroll
  for (int j = 0; j < 4; j++){
    atomicAdd(&lb[tx*4+j], ab[j]);
    atomicAdd(&lf[tx*4+j], af[j]);
  }
  __syncthreads();
  if (tid < 128){
    atomicAdd(&bwm[tid], lb[tid]);
    atomicAdd(&fwm[tid], lf[tid]);
  }
}

// flash-style fused read addressing
__global__ __launch_bounds__(256) void k_flash(
    const _Float16* __restrict__ Q, const _Float16* __restrict__ Kh,
    const _Float16* __restrict__ Vt,
    float* __restrict__ pacc, float* __restrict__ pm, float* __restrict__ pl)
{
  __shared__ _Float16 Pl[4][16][32];
  __shared__ float cmb[4][2080];
  __shared__ float scl[4][16];
  const int tid = threadIdx.x;
  const int qt = blockIdx.x >> 2, kc = blockIdx.x & 3;
  const int wv = tid >> 6, lane = tid & 63;
  const int fq = lane >> 4, fr = lane & 15;
  const int kw0 = kc*512 + wv*128;

  half8 aq[4];
  #pragma unroll
  for (int c = 0; c < 4; c++)
    aq[c] = *(const half8*)(Q + (size_t)(qt*16 + fr)*128 + c*32 + fq*8);

  float m[4] = {-3.0e38f,-3.0e38f,-3.0e38f,-3.0e38f};
  float l[4] = {0.f,0.f,0.f,0.f};
  float4v acc[8] = {};
  for (int s = 0; s < 4; s++){
    const int kb = kw0 + s*32;
    float4v S0 = {0,0,0,0}, S1 = {0,0,0,0};
    #pragma unroll
    for (int c = 0; c < 4; c++){
      half8 b0 = *(const half8*)(Kh + (size_t)(kb + fr)*128      + c*32 + fq*8);
      half8 b1 = *(const half8*)(Kh + (size_t)(kb + 16 + fr)*128 + c*32 + fq*8);
      S0 = __builtin_amdgcn_mfma_f32_16x16x32_f16(aq[c], b0, S0, 0, 0, 0);
      S1 = __builtin_amdgcn_mfma_f32_16x16x32_f16(aq[c], b1, S1, 0, 0, 0);
    }
    float mt[4], ps[4];
    #pragma unroll
    for (int i = 0; i < 4; i++) mt[i] = fmaxf(S0[i], S1[i]);
    #pragma unroll
    for (int o = 1; o < 16; o <<= 1){
      #pragma unroll
      for (int i = 0; i < 4; i++) mt[i] = fmaxf(mt[i], __shfl_xor(mt[i], o));
    }
    #pragma unroll
    for (int i = 0; i < 4; i++){
      float mn = fmaxf(m[i], mt[i]);
      float al = expf(m[i] - mn);
      float p0 = expf(S0[i] - mn), p1 = expf(S1[i] - mn);
      S0[i] = p0; S1[i] = p1;
      ps[i] = p0 + p1;
      l[i] *= al;
      m[i] = mn;
      #pragma unroll
      for (int c = 0; c < 8; c++) acc[c][i] *= al;
    }
    #pragma unroll
    for (int o = 1; o < 16; o <<= 1){
      #pragma unroll
      for (int i = 0; i < 4; i++) ps[i] += __shfl_xor(ps[i], o);
    }
    #pragma unroll
    for (int i = 0; i < 4; i++) l[i] += ps[i];
    #pragma unroll
    for (int i = 0; i < 4; i++){
      Pl[wv][fq*4+i][fr]      = (_Float16)S0[i];
      Pl[wv][fq*4+i][16 + fr] = (_Float16)S1[i];
    }
    half8 pf = *(half8*)&Pl[wv][fr][fq*8];
    #pragma unroll
    for (int c = 0; c < 8; c++){
      half8 bv = *(const half8*)(Vt + (size_t)(c*16 + fr)*2048 + kb + fq*8);
      acc[c] = __builtin_amdgcn_mfma_f32_16x16x32_f16(pf, bv, acc[c], 0, 0, 0);
    }
  }
  if (fr == 0){
    #pragma unroll
    for (int i = 0; i < 4; i++){
      cmb[wv][fq*4+i]      = m[i];
      cmb[wv][16 + fq*4+i] = l[i];
    }
  }
  #pragma unroll
  for (int c = 0; c < 8; c++)
    #pragma unroll
    for (int i = 0; i < 4; i++)
      cmb[wv][32 + (fq*4+i)*128 + c*16 + fr] = acc[c][i];
  __syncthreads();
  if (tid < 16){
    float mm = fmaxf(fmaxf(cmb[0][tid], cmb[1][tid]), fmaxf(cmb[2][tid], cmb[3][tid]));
    float ll = 0.f;
    #pragma unroll
    for (int w = 0; w < 4; w++){
      float e = expf(cmb[w][tid] - mm);
      scl[w][tid] = e;
      ll += e * cmb[w][16 + tid];
    }
    pm[blockIdx.x*16 + tid] = mm;
    pl[blockIdx.x*16 + tid] = ll;
  }
  __syncthreads();
  for (int e = tid; e < 2048; e += 256){
    int q = e >> 7;
    float a = scl[0][q]*cmb[0][32+e] + scl[1][q]*cmb[1][32+e]
            + scl[2][q]*cmb[2][32+e] + scl[3][q]*cmb[3][32+e];
    pacc[(size_t)blockIdx.x*2048 + e] = a;
  }
}

// fused: flash partial combine + read-mode mix + hro concat (h from h_h)
__global__ void k_hro_comb(const _Float16* __restrict__ h, const float* __restrict__ pacc,
                           const float* __restrict__ pm, const float* __restrict__ pl,
                           const float* __restrict__ rm0, const float* __restrict__ rm1,
                           const float* __restrict__ rm2, const float* __restrict__ bwm,
                           const float* __restrict__ fwm, _Float16* __restrict__ hro){
  int idx = blockIdx.x*256 + threadIdx.x;   // 256*1536
  int b = idx / 1536, k = idx - b*1536;
  if (k < 1024){
    hro[idx] = h[b*1024 + k];
  } else {
    int r = k - 1024, rh = r >> 7, d = r & 127;
    int row = b*4 + rh, qt = row >> 4, q = row & 15;
    float mm = -3.0e38f;
    #pragma unroll
    for (int kc = 0; kc < 4; kc++) mm = fmaxf(mm, pm[(qt*4+kc)*16 + q]);
    float num = 0.f, den = 0.f;
    #pragma unroll
    for (int kc = 0; kc < 4; kc++){
      float e = expf(pm[(qt*4+kc)*16 + q] - mm);
      den += e * pl[(qt*4+kc)*16 + q];
      num += e * pacc[(size_t)(qt*4+kc)*2048 + q*128 + d];
    }
    float pv = num / den;
    hro[idx] = (_Float16)(rm0[row]*pv + rm1[row]*bwm[d] + rm2[row]*fwm[d]);
  }
}

// ---------------- launcher ----------------

extern "C" void kernel_launch(void* const* d_in, const int* in_sizes, int n_in,
                              void* d_out, int out_size, void* d_ws, size_t ws_size,
                              hipStream_t stream)
{
  const float* x     = (const float*)d_in[0];
  const float* mem   = (const float*)d_in[1];
  const float* usage = (const float*)d_in[2];
  const float* link  = (const float*)d_in[3];
  const float* W_ih  = (const float*)d_in[4];
  // d_in[5] = W_hh: unused (h0 = 0)
  const float* b_ih  = (const float*)d_in[6];
  const float* b_hh  = (const float*)d_in[7];
  const float* W_if  = (const float*)d_in[8];
  const float* b_if  = (const float*)d_in[9];
  const float* W_out = (const float*)d_in[10];
  const float* b_out = (const float*)d_in[11];
  float* out = (float*)d_out;
  float* ws  = (float*)d_ws;

  // fp32 scratch
  float* cm     = ws + 0;         // 128   (zero region: cm,csl,bwm,fwm = 2432)
  float* csl    = ws + 128;       // 2048
  float* bwm    = ws + 2176;      // 128
  float* fwm    = ws + 2304;      // 128
  float* bw     = ws + 2688;      // 2048
  float* fw     = ws + 4736;      // 2048
  float* wg     = ws + 6784;      // 256
  float* ag     = ws + 7040;      // 256
  float* rm0    = ws + 7296;      // 1024
  float* rm1    = ws + 8320;      // 1024
  float* rm2    = ws + 9344;      // 1024
  float* alloc  = ws + 10368;     // 2048
  float* rsl    = ws + 12416;     // 2048
  float* ev     = ws + 14464;     // 32768 (B x 128)
  float* av     = ws + 47232;     // 32768
  float* g      = ws + 80000;     // 1048576 (B x 4096 LSTM gates)
  float* itf    = ws + 1128576;   // 201472 (B x 787)
  float* ww     = ws + 1330048;   // 524288 (B x 2048)
  float* pacc   = ws + 1854336;   // 524288 (256 blocks x 2048)
  float* pm     = ws + 2378624;   // 4096
  float* pl     = ws + 2382720;   // 4096
  // fp16 scratch
  _Float16* wv_h    = (_Float16*)(ws + 2386816);  //  32,768 h
  _Float16* mem_h   = (_Float16*)(ws + 2403200);  // 262,144 h (row-normalized)
  _Float16* memn_h  = (_Float16*)(ws + 2534272);  // 262,144 h (row-normalized)
  _Float16* memnT_h = (_Float16*)(ws + 2665344);  // 262,144 h (transposed raw)
  _Float16* rks_h   = (_Float16*)(ws + 2796416);  // 131,072 h
  _Float16* hro_h   = (_Float16*)(ws + 2861952);  // 393,216 h
  _Float16* cin_h   = (_Float16*)(ws + 3058560);  // 393,216 h
  _Float16* h_h     = (_Float16*)(ws + 3255168);  // 262,144 h
  // total ~3.39M floats = 13.5 MB

  // stage 0: zero atomic accumulators
  k_zero<<<10, 256, 0, stream>>>(ws, 2432);

  // stage 1 (merged): mem colsum+rownorm | link row/col sums | allocation
  k_stage1<<<672, 256, 0, stream>>>(mem, cm, mem_h, usage, alloc, link, rsl, csl);
  k_cin   <<<1536, 256, 0, stream>>>(x, cm, cin_h);

  // stage 2: LSTM controller (B = W_ih fp32, deferred-cvt)
  gemm_t<float><<<dim3(64,8), 256, 0, stream>>>(cin_h, W_ih, g, 256, 4096, 1536, b_ih, b_hh);
  k_lstm<<<1024, 256, 0, stream>>>(g, h_h);

  // stage 3: interface (B = W_if fp32, deferred-cvt)
  gemm_t<float><<<dim3(13,8), 256, 0, stream>>>(h_h, W_if, itf, 256, 787, 1024, b_if, nullptr);
  k_parse<<<256, 128, 0, stream>>>(itf, wv_h, ev, av, wg, ag, rm0, rm1, rm2, rks_h);

  // stage 4: write weighting (softmax + write-gates fused)
  gemm_t<_Float16><<<dim3(32,8), 256, 0, stream>>>(wv_h, mem_h, ww, 256, 2048, 128, nullptr, nullptr);
  k_softmax_ww<<<256, 256, 0, stream>>>(ww, alloc, wg, ag);

  // stage 5: link-derived read vectors (Salloc reduced in-kernel; tb analytic)
  k_bwfw<<<32, 256, 0, stream>>>(ww, wg, ag, alloc, rsl, csl, bw, fw);

  // stage 6: memory update (update + norms + fp16 emits + transpose + bwm/fwm fused)
  k_memupdate_fused<<<64, 256, 0, stream>>>(ww, ev, av, mem, bw, fw, memn_h, memnT_h, bwm, fwm);

  // stage 7: flash-fused read addressing (sim never materialized)
  k_flash<<<256, 256, 0, stream>>>(rks_h, memn_h, memnT_h, pacc, pm, pl);

  // stage 8: combine + output projection (B = W_out fp32, deferred-cvt)
  k_hro_comb<<<1536, 256, 0, stream>>>(h_h, pacc, pm, pl, rm0, rm1, rm2, bwm, fwm, hro_h);
  gemm_t<float><<<dim3(16,8), 256, 0, stream>>>(hro_h, W_out, out, 256, 1024, 1536, b_out, nullptr);

  (void)in_sizes; (void)n_in; (void)out_size; (void)ws_size;
}

// Round 5
// 236.334 us; speedup vs baseline: 1.1389x; 1.1389x over previous
//
#include <hip/hip_runtime.h>
#include <cmath>

#define DEVI __device__ __forceinline__

DEVI float sigm(float x){ return 1.f/(1.f+expf(-x)); }

typedef __attribute__((ext_vector_type(8))) _Float16 half8;
typedef __attribute__((ext_vector_type(4))) _Float16 half4;
typedef __attribute__((ext_vector_type(4))) float float4v;

// ---------------- utility ----------------

__global__ void k_zero(float* __restrict__ p, int n){
  int i = blockIdx.x*256 + threadIdx.x;
  if (i < n) p[i] = 0.f;
}

// merged independent input-stage kernel, sized for latency hiding:
//   blocks [0,128):   mem column sums (atomic cm) + row-L2-norm fp16 copy, 4-row ILP
//   blocks [128,384): link row sums + col-sum PARTIALS (256 blocks x 8 rows, reg-resident)
//   blocks [384,896): allocation weighting, one n per wave
__global__ __launch_bounds__(256) void k_stage1(
    const float* __restrict__ mem, float* __restrict__ cm, _Float16* __restrict__ mem_h,
    const float* __restrict__ usage, float* __restrict__ alloc,
    const float* __restrict__ link, float* __restrict__ rsl, float* __restrict__ cslp)
{
  __shared__ float smem[4][132];
  const int blk = blockIdx.x, t = threadIdx.x;
  const int wv = t >> 6, lane = t & 63;

  if (blk < 128){
    // ---- prep_mem: 16 rows/block, 4 rows/wave, independent reduce chains ----
    int rbase = blk*16 + wv*4;
    float x0[4], x1[4], ss[4];
    #pragma unroll
    for (int u = 0; u < 4; u++){
      const float* a = mem + (size_t)(rbase+u)*128;
      x0[u] = a[lane]; x1[u] = a[lane+64];
    }
    #pragma unroll
    for (int u = 0; u < 4; u++) ss[u] = x0[u]*x0[u] + x1[u]*x1[u];
    #pragma unroll
    for (int o = 1; o < 64; o <<= 1){
      #pragma unroll
      for (int u = 0; u < 4; u++) ss[u] += __shfl_xor(ss[u], o);
    }
    float c0 = 0.f, c1 = 0.f;
    #pragma unroll
    for (int u = 0; u < 4; u++){
      float invn = 1.f / fmaxf(sqrtf(ss[u]), 1e-12f);
      mem_h[(size_t)(rbase+u)*128 + lane]      = (_Float16)(x0[u]*invn);
      mem_h[(size_t)(rbase+u)*128 + 64 + lane] = (_Float16)(x1[u]*invn);
      c0 += x0[u]; c1 += x1[u];
    }
    smem[wv][lane] = c0; smem[wv][64+lane] = c1;
    __syncthreads();
    if (t < 128) atomicAdd(&cm[t], smem[0][t]+smem[1][t]+smem[2][t]+smem[3][t]);
  } else if (blk < 384){
    // ---- link: 8 rows/block, all loads independent, reduces at the end ----
    int pb = blk - 128;
    int r0 = pb*8;
    int c0 = t*8;
    float4v v0[8], v1[8];
    #pragma unroll
    for (int u = 0; u < 8; u++){
      const float* lp = link + (size_t)(r0+u)*2048 + c0;
      v0[u] = *(const float4v*)lp;
      v1[u] = *(const float4v*)(lp+4);
    }
    float colacc[8];
    #pragma unroll
    for (int j = 0; j < 8; j++) colacc[j] = 0.f;
    float rowpart[8];
    #pragma unroll
    for (int u = 0; u < 8; u++){
      float s = 0.f;
      #pragma unroll
      for (int j = 0; j < 4; j++){
        colacc[j]   += v0[u][j]; colacc[4+j] += v1[u][j];
        s += v0[u][j] + v1[u][j];
      }
      rowpart[u] = s;
    }
    #pragma unroll
    for (int o = 1; o < 64; o <<= 1){
      #pragma unroll
      for (int u = 0; u < 8; u++) rowpart[u] += __shfl_xor(rowpart[u], o);
    }
    if (lane == 0){
      #pragma unroll
      for (int u = 0; u < 8; u++) smem[wv][u] = rowpart[u];
    }
    __syncthreads();
    if (t < 8) rsl[r0+t] = smem[0][t]+smem[1][t]+smem[2][t]+smem[3][t];
    // coalesced per-block column partials (no global atomics)
    float4v w0, w1;
    #pragma unroll
    for (int j = 0; j < 4; j++){ w0[j] = colacc[j]; w1[j] = colacc[4+j]; }
    *(float4v*)&cslp[(size_t)pb*2048 + c0]     = w0;
    *(float4v*)&cslp[(size_t)pb*2048 + c0 + 4] = w1;
  } else {
    // ---- alloc: one n per wave, 4 waves/block, 512 blocks ----
    int n = (blk - 384)*4 + wv;
    float un = usage[n];
    float prod = 1.f;
    #pragma unroll
    for (int i = 0; i < 32; i++){
      int m = lane + i*64;
      float um = usage[m];
      bool before = (um < un) || (um == un && m < n);
      prod *= before ? (1.f - um) : 1.f;
    }
    #pragma unroll
    for (int o = 32; o > 0; o >>= 1) prod *= __shfl_xor(prod, o);
    if (lane == 0) alloc[n] = un * prod;
  }
}

// blocks [0,1536): cin_h[b,k] = fp16( k<1024 ? x[b,k] : cm[(k-1024)%128]/2048 )
// blocks [1536,1568): csl[col] = sum over 256 cslp partials (coalesced, L2-hot)
__global__ __launch_bounds__(256) void k_cin_csl(const float* __restrict__ x,
    const float* __restrict__ cm, _Float16* __restrict__ cin,
    const float* __restrict__ cslp, float* __restrict__ csl)
{
  __shared__ float sm[4][64];
  int blk = blockIdx.x, t = threadIdx.x;
  if (blk < 1536){
    int idx = blk*256 + t;                    // 256*1536
    int b = idx / 1536, k = idx - b*1536;
    float v = (k < 1024) ? x[b*1024 + k] : cm[(k-1024) & 127] * (1.f/2048.f);
    cin[idx] = (_Float16)v;
  } else {
    int j = blk - 1536;                       // 0..31, 64 cols each
    int tl = t & 63, q = t >> 6;
    int col = j*64 + tl;
    float s = 0.f;
    for (int p = q*64; p < q*64 + 64; p += 4){
      s += cslp[(size_t)(p+0)*2048 + col] + cslp[(size_t)(p+1)*2048 + col]
         + cslp[(size_t)(p+2)*2048 + col] + cslp[(size_t)(p+3)*2048 + col];
    }
    sm[q][tl] = s;
    __syncthreads();
    if (q == 0) csl[col] = sm[0][tl]+sm[1][tl]+sm[2][tl]+sm[3][tl];
  }
}

// LSTM gate activation -> fp16 h
__global__ void k_lstm(const float* __restrict__ g, _Float16* __restrict__ h){
  int idx = blockIdx.x*256 + threadIdx.x;    // 256*1024
  int b = idx >> 10, j = idx & 1023;
  const float* gr = g + (size_t)b*4096;
  float c = sigm(gr[j]) * tanhf(gr[2048 + j]);
  h[idx] = (_Float16)(sigm(gr[3072 + j]) * tanhf(c));
}

// ---------------- fp16 MFMA NT GEMM: C = A @ B^T + bias1 + bias2 ----------------
// A is fp16. B is fp16 or fp32; fp32 is loaded RAW into registers and converted
// only at the LDS-write point (after the MFMA section) so the vmcnt wait does not
// land in front of the compute.
#define QA 264
#define QB 520

template<typename TB> struct BReg;
template<> struct BReg<_Float16>{
  half8 v;
  DEVI void load(const _Float16* p){ v = *(const half8*)p; }
  DEVI half8 get() const { return v; }
};
template<> struct BReg<float>{
  float4v a, b;
  DEVI void load(const float* p){ a = *(const float4v*)p; b = *(const float4v*)(p+4); }
  DEVI half8 get() const {
    half8 h;
    #pragma unroll
    for (int j = 0; j < 4; j++){ h[j] = (_Float16)a[j]; h[4+j] = (_Float16)b[j]; }
    return h;
  }
};

template<typename TB>
__global__ __launch_bounds__(256) void gemm_t(
    const _Float16* __restrict__ A, const TB* __restrict__ Bm, float* __restrict__ C,
    int M, int N, int K,
    const float* __restrict__ bias1, const float* __restrict__ bias2)
{
  __shared__ _Float16 Ah[2][8*QA];
  __shared__ _Float16 Bh[2][8*QB];
  const int tid = threadIdx.x;
  const int m0 = blockIdx.y*32, n0 = blockIdx.x*64;
  const int T = K >> 6;
  const int arow = tid >> 3, aq = tid & 7;
  const int brow = tid >> 3, bq = tid & 7;
  int nB0 = n0 + brow;      if (nB0 >= N) nB0 = N - 1;
  int nB1 = n0 + brow + 32; if (nB1 >= N) nB1 = N - 1;
  const _Float16* Aptr = A + (size_t)(m0 + arow)*K + aq*8;
  const TB* Bp0 = Bm + (size_t)nB0*K + bq*8;
  const TB* Bp1 = Bm + (size_t)nB1*K + bq*8;
  const int wA  = aq*QA + arow*8;
  const int wB0 = bq*QB + brow*8;
  const int wB1 = bq*QB + (brow+32)*8;
  const int wv_ = tid >> 6, lane = tid & 63;
  const int fq = lane >> 4, fr = lane & 15;
  const int m16 = (wv_ & 1)*16, nb = (wv_ >> 1)*32;

  half8 ra;
  BReg<TB> rb0, rb1;
  ra = *(const half8*)(Aptr);
  rb0.load(Bp0);
  rb1.load(Bp1);
  *(half8*)&Ah[0][wA]  = ra;
  *(half8*)&Bh[0][wB0] = rb0.get();
  *(half8*)&Bh[0][wB1] = rb1.get();
  __syncthreads();

  float4v acc0 = {0.f,0.f,0.f,0.f}, acc1 = {0.f,0.f,0.f,0.f};
  for (int t = 0; t < T; t++){
    const int cur = t & 1, nxt = cur ^ 1;
    if (t+1 < T){
      ra = *(const half8*)(Aptr + (t+1)*64);
      rb0.load(Bp0 + (t+1)*64);
      rb1.load(Bp1 + (t+1)*64);
    }
    #pragma unroll
    for (int s = 0; s < 2; s++){
      int q = s*4 + fq;
      half8 a  = *(half8*)&Ah[cur][q*QA + (m16+fr)*8];
      half8 b0 = *(half8*)&Bh[cur][q*QB + (nb+fr)*8];
      half8 b1 = *(half8*)&Bh[cur][q*QB + (nb+16+fr)*8];
      acc0 = __builtin_amdgcn_mfma_f32_16x16x32_f16(a, b0, acc0, 0, 0, 0);
      acc1 = __builtin_amdgcn_mfma_f32_16x16x32_f16(a, b1, acc1, 0, 0, 0);
    }
    if (t+1 < T){
      *(half8*)&Ah[nxt][wA]  = ra;
      *(half8*)&Bh[nxt][wB0] = rb0.get();   // cvt happens here, after the MFMAs
      *(half8*)&Bh[nxt][wB1] = rb1.get();
    }
    __syncthreads();
  }

  const int colA = n0 + nb + fr, colB = colA + 16;
  #pragma unroll
  for (int i = 0; i < 4; i++){
    int m = m0 + m16 + fq*4 + i;
    if (colA < N){
      float v = acc0[i];
      if (bias1) v += bias1[colA];
      if (bias2) v += bias2[colA];
      C[(size_t)m*N + colA] = v;
    }
    if (colB < N){
      float v = acc1[i];
      if (bias1) v += bias1[colB];
      if (bias2) v += bias2[colB];
      C[(size_t)m*N + colB] = v;
    }
  }
}

DEVI float blockReduce128(float v, float* lds2){
  #pragma unroll
  for (int o = 32; o > 0; o >>= 1) v += __shfl_xor(v, o);
  int w = threadIdx.x >> 6;
  __syncthreads();
  if ((threadIdx.x & 63) == 0) lds2[w] = v;
  __syncthreads();
  return lds2[0] + lds2[1];
}

// parse itf; wv_h has invwv folded, rks_h has invk*str folded
__global__ __launch_bounds__(128) void k_parse(const float* __restrict__ itf,
    _Float16* __restrict__ wv_h, float* __restrict__ ev, float* __restrict__ av,
    float* __restrict__ wg_, float* __restrict__ ag_,
    float* __restrict__ rm0, float* __restrict__ rm1, float* __restrict__ rm2,
    _Float16* __restrict__ rks_h)
{
  __shared__ float red[2];
  int b = blockIdx.x, t = threadIdx.x;
  const float* it = itf + (size_t)b*787;
  float wg = sigm(it[256]);
  float ag = sigm(it[257]);
  if (t == 0){ wg_[b] = wg; ag_[b] = ag; }
  float w = it[t];
  av[b*128 + t] = w * wg;
  ev[b*128 + t] = sigm(it[128 + t]) * wg;
  float ss = blockReduce128(w*w, red);
  float invwv = 1.f / fmaxf(sqrtf(ss), 1e-12f);
  wv_h[b*128 + t] = (_Float16)(w * invwv);
  if (t < 4){
    int rr = t;
    float m0v = it[259 + rr*3 + 0], m1v = it[259 + rr*3 + 1], m2v = it[259 + rr*3 + 2];
    float mx = fmaxf(m0v, fmaxf(m1v, m2v));
    float e0 = expf(m0v - mx), e1 = expf(m1v - mx), e2 = expf(m2v - mx);
    float inv = 1.f / (e0 + e1 + e2);
    rm0[b*4 + rr] = e0*inv; rm1[b*4 + rr] = e1*inv; rm2[b*4 + rr] = e2*inv;
  }
  #pragma unroll
  for (int rr = 0; rr < 4; rr++){
    float kv = it[275 + rr*128 + t];
    float ks = blockReduce128(kv*kv, red);
    float sx = it[271 + rr];
    float str = fmaxf(sx, 0.f) + log1pf(expf(-fabsf(sx)));
    float invk = 1.f / fmaxf(sqrtf(ks), 1e-12f);
    rks_h[((size_t)b*4 + rr)*128 + t] = (_Float16)(kv * invk * str);
  }
}

// softmax over 2048-wide rows, fused write-weighting epilogue
__global__ __launch_bounds__(256) void k_softmax_ww(float* __restrict__ P,
    const float* __restrict__ alloc, const float* __restrict__ wg, const float* __restrict__ ag){
  __shared__ float red[4];
  float* p = P + (size_t)blockIdx.x*2048;
  int t = threadIdx.x;
  float r[8];
  float mx = -3.4e38f;
  #pragma unroll
  for (int i = 0; i < 8; i++){ r[i] = p[t + i*256]; mx = fmaxf(mx, r[i]); }
  #pragma unroll
  for (int o = 32; o > 0; o >>= 1) mx = fmaxf(mx, __shfl_xor(mx, o));
  if ((t & 63) == 0) red[t >> 6] = mx;
  __syncthreads();
  mx = fmaxf(fmaxf(red[0], red[1]), fmaxf(red[2], red[3]));
  float s = 0.f;
  #pragma unroll
  for (int i = 0; i < 8; i++){ r[i] = expf(r[i] - mx); s += r[i]; }
  #pragma unroll
  for (int o = 32; o > 0; o >>= 1) s += __shfl_xor(s, o);
  __syncthreads();
  if ((t & 63) == 0) red[t >> 6] = s;
  __syncthreads();
  s = red[0] + red[1] + red[2] + red[3];
  float inv = 1.f / s;
  float wgb = wg[blockIdx.x], agb = ag[blockIdx.x];
  #pragma unroll
  for (int i = 0; i < 8; i++){
    int col = t + i*256;
    p[col] = wgb*(0.5f*r[i]*inv + 0.5f*alloc[col]*agb);
  }
}

// bw/fw from link sums + lu sums; Salloc reduced per-block from alloc (no global atomic);
// tb analytic: tb[b] = wg[b]*(0.5 + 0.5*ag[b]*Salloc)
__global__ __launch_bounds__(256) void k_bwfw(const float* __restrict__ ww,
                       const float* __restrict__ wg, const float* __restrict__ ag,
                       const float* __restrict__ alloc,
                       const float* __restrict__ rowsum, const float* __restrict__ colsum,
                       float* __restrict__ bw, float* __restrict__ fw){
  __shared__ float sq[4][64], sd[4][64];
  __shared__ float sred[4];
  __shared__ float tbs[256];
  int t = threadIdx.x & 63, z = threadIdx.x >> 6;
  int m = blockIdx.x*64 + t;
  // Salloc: redundant per-block tree reduce over alloc[0..2048)
  float sa = 0.f;
  #pragma unroll
  for (int i = 0; i < 8; i++) sa += alloc[threadIdx.x + i*256];
  #pragma unroll
  for (int o = 32; o > 0; o >>= 1) sa += __shfl_xor(sa, o);
  if (t == 0) sred[z] = sa;
  __syncthreads();
  sa = (sred[0]+sred[1]) + (sred[2]+sred[3]);
  tbs[threadIdx.x] = wg[threadIdx.x]*(0.5f + 0.5f*ag[threadIdx.x]*sa);
  __syncthreads();
  float q = 0.f, dd = 0.f;
  for (int b = z*64; b < z*64 + 64; b += 4){
    float w0 = ww[(size_t)(b+0)*2048 + m];
    float w1 = ww[(size_t)(b+1)*2048 + m];
    float w2 = ww[(size_t)(b+2)*2048 + m];
    float w3 = ww[(size_t)(b+3)*2048 + m];
    q  = fmaf(tbs[b+0], w0, q);  dd = fmaf(w0, w0, dd);
    q  = fmaf(tbs[b+1], w1, q);  dd = fmaf(w1, w1, dd);
    q  = fmaf(tbs[b+2], w2, q);  dd = fmaf(w2, w2, dd);
    q  = fmaf(tbs[b+3], w3, q);  dd = fmaf(w3, w3, dd);
  }
  sq[z][t] = q; sd[z][t] = dd;
  __syncthreads();
  if (z == 0){
    q  = sq[0][t] + sq[1][t] + sq[2][t] + sq[3][t];
    dd = sd[0][t] + sd[1][t] + sd[2][t] + sd[3][t];
    float lus = (q - dd) * (1.f/256.f);
    bw[m] = (0.9f*colsum[m] + 0.1f*lus) * (1.f/2048.f);
    fw[m] = (0.9f*rowsum[m] + 0.1f*lus) * (1.f/2048.f);
  }
}

// fused memory update: memn = mem*(1-ww^T@ev/B)+ww^T@av/B, emit fp16 normalized
// (memn_h) + fp16 raw TRANSPOSED (memnT_h), and bwm/fwm partials (atomic, pre-zeroed).
__global__ __launch_bounds__(256) void k_memupdate_fused(const float* __restrict__ ww,
    const float* __restrict__ ev, const float* __restrict__ av,
    const float* __restrict__ mem, const float* __restrict__ bw, const float* __restrict__ fw,
    _Float16* __restrict__ memn_h, _Float16* __restrict__ memnT_h,
    float* __restrict__ bwm, float* __restrict__ fwm)
{
  __shared__ float Ws[16][34];
  __shared__ float Es[16][132], Vs[16][132];
  __shared__ float lb[128], lf[128];
  __shared__ _Float16 Traw[32][132];
  const int n0 = blockIdx.x*32;
  const int tid = threadIdx.x, tx = tid & 31, ty = tid >> 5;
  if (tid < 128){ lb[tid] = 0.f; lf[tid] = 0.f; }
  const int wk = tid >> 4, wn = (tid & 15)*2;
  const int ek = tid >> 4, ec = (tid & 15)*8;
  float ae[4][4] = {}, aa[4][4] = {};
  for (int k0 = 0; k0 < 256; k0 += 16){
    float2 vw  = *(const float2*)(ww + (size_t)(k0+wk)*2048 + n0 + wn);
    float4 ve0 = *(const float4*)(ev + (size_t)(k0+ek)*128 + ec);
    float4 ve1 = *(const float4*)(ev + (size_t)(k0+ek)*128 + ec + 4);
    float4 va0 = *(const float4*)(av + (size_t)(k0+ek)*128 + ec);
    float4 va1 = *(const float4*)(av + (size_t)(k0+ek)*128 + ec + 4);
    __syncthreads();
    Ws[wk][wn] = vw.x; Ws[wk][wn+1] = vw.y;
    *(float4*)&Es[ek][ec] = ve0; *(float4*)&Es[ek][ec+4] = ve1;
    *(float4*)&Vs[ek][ec] = va0; *(float4*)&Vs[ek][ec+4] = va1;
    __syncthreads();
    #pragma unroll
    for (int k = 0; k < 16; k++){
      float a[4], e[4], v[4];
      #pragma unroll
      for (int i = 0; i < 4; i++) a[i] = Ws[k][ty*4+i];
      #pragma unroll
      for (int j = 0; j < 4; j++){ e[j] = Es[k][tx*4+j]; v[j] = Vs[k][tx*4+j]; }
      #pragma unroll
      for (int i = 0; i < 4; i++)
        #pragma unroll
        for (int j = 0; j < 4; j++){
          ae[i][j] = fmaf(a[i], e[j], ae[i][j]);
          aa[i][j] = fmaf(a[i], v[j], aa[i][j]);
        }
    }
  }
  float ab[4] = {0,0,0,0}, af[4] = {0,0,0,0};
  #pragma unroll
  for (int i = 0; i < 4; i++){
    int n = n0 + ty*4 + i;
    float bwn = bw[n], fwn = fw[n];
    float v[4]; float ss = 0.f;
    #pragma unroll
    for (int j = 0; j < 4; j++){
      int d = tx*4 + j;
      float em = ae[i][j]*(1.f/256.f), am = aa[i][j]*(1.f/256.f);
      float mv = mem[(size_t)n*128 + d]*(1.f - em) + am;
      v[j] = mv; ss += mv*mv;
      ab[j] = fmaf(bwn, mv, ab[j]);
      af[j] = fmaf(fwn, mv, af[j]);
    }
    #pragma unroll
    for (int o = 1; o < 32; o <<= 1) ss += __shfl_xor(ss, o);
    float invn = 1.f / fmaxf(sqrtf(ss), 1e-12f);
    half4 hn, hr;
    #pragma unroll
    for (int j = 0; j < 4; j++){ hn[j] = (_Float16)(v[j]*invn); hr[j] = (_Float16)v[j]; }
    *(half4*)(memn_h + (size_t)n*128 + tx*4) = hn;
    *(half4*)&Traw[ty*4+i][tx*4] = hr;
  }
  __syncthreads();
  // transposed emit: thread -> (d, 16-col segment)
  {
    int d = tid >> 1, seg = (tid & 1)*16;
    half8 o0, o1;
    #pragma unroll
    for (int j = 0; j < 8; j++){ o0[j] = Traw[seg+j][d]; o1[j] = Traw[seg+8+j][d]; }
    *(half8*)(memnT_h + (size_t)d*2048 + n0 + seg)     = o0;
    *(half8*)(memnT_h + (size_t)d*2048 + n0 + seg + 8) = o1;
  }
  #pragma unroll
  for (int j = 0; j < 4; j++){
    atomicAdd(&lb[tx*4+j], ab[j]);
    atomicAdd(&lf[tx*4+j], af[j]);
  }
  __syncthreads();
  if (tid < 128){
    atomicAdd(&bwm[tid], lb[tid]);
    atomicAdd(&fwm[tid], lf[tid]);
  }
}

// flash-style fused read addressing
__global__ __launch_bounds__(256) void k_flash(
    const _Float16* __restrict__ Q, const _Float16* __restrict__ Kh,
    const _Float16* __restrict__ Vt,
    float* __restrict__ pacc, float* __restrict__ pm, float* __restrict__ pl)
{
  __shared__ _Float16 Pl[4][16][32];
  __shared__ float cmb[4][2080];
  __shared__ float scl[4][16];
  const int tid = threadIdx.x;
  const int qt = blockIdx.x >> 2, kc = blockIdx.x & 3;
  const int wv = tid >> 6, lane = tid & 63;
  const int fq = lane >> 4, fr = lane & 15;
  const int kw0 = kc*512 + wv*128;

  half8 aq[4];
  #pragma unroll
  for (int c = 0; c < 4; c++)
    aq[c] = *(const half8*)(Q + (size_t)(qt*16 + fr)*128 + c*32 + fq*8);

  float m[4] = {-3.0e38f,-3.0e38f,-3.0e38f,-3.0e38f};
  float l[4] = {0.f,0.f,0.f,0.f};
  float4v acc[8] = {};
  for (int s = 0; s < 4; s++){
    const int kb = kw0 + s*32;
    float4v S0 = {0,0,0,0}, S1 = {0,0,0,0};
    #pragma unroll
    for (int c = 0; c < 4; c++){
      half8 b0 = *(const half8*)(Kh + (size_t)(kb + fr)*128      + c*32 + fq*8);
      half8 b1 = *(const half8*)(Kh + (size_t)(kb + 16 + fr)*128 + c*32 + fq*8);
      S0 = __builtin_amdgcn_mfma_f32_16x16x32_f16(aq[c], b0, S0, 0, 0, 0);
      S1 = __builtin_amdgcn_mfma_f32_16x16x32_f16(aq[c], b1, S1, 0, 0, 0);
    }
    float mt[4], ps[4];
    #pragma unroll
    for (int i = 0; i < 4; i++) mt[i] = fmaxf(S0[i], S1[i]);
    #pragma unroll
    for (int o = 1; o < 16; o <<= 1){
      #pragma unroll
      for (int i = 0; i < 4; i++) mt[i] = fmaxf(mt[i], __shfl_xor(mt[i], o));
    }
    #pragma unroll
    for (int i = 0; i < 4; i++){
      float mn = fmaxf(m[i], mt[i]);
      float al = expf(m[i] - mn);
      float p0 = expf(S0[i] - mn), p1 = expf(S1[i] - mn);
      S0[i] = p0; S1[i] = p1;
      ps[i] = p0 + p1;
      l[i] *= al;
      m[i] = mn;
      #pragma unroll
      for (int c = 0; c < 8; c++) acc[c][i] *= al;
    }
    #pragma unroll
    for (int o = 1; o < 16; o <<= 1){
      #pragma unroll
      for (int i = 0; i < 4; i++) ps[i] += __shfl_xor(ps[i], o);
    }
    #pragma unroll
    for (int i = 0; i < 4; i++) l[i] += ps[i];
    #pragma unroll
    for (int i = 0; i < 4; i++){
      Pl[wv][fq*4+i][fr]      = (_Float16)S0[i];
      Pl[wv][fq*4+i][16 + fr] = (_Float16)S1[i];
    }
    half8 pf = *(half8*)&Pl[wv][fr][fq*8];
    #pragma unroll
    for (int c = 0; c < 8; c++){
      half8 bv = *(const half8*)(Vt + (size_t)(c*16 + fr)*2048 + kb + fq*8);
      acc[c] = __builtin_amdgcn_mfma_f32_16x16x32_f16(pf, bv, acc[c], 0, 0, 0);
    }
  }
  if (fr == 0){
    #pragma unroll
    for (int i = 0; i < 4; i++){
      cmb[wv][fq*4+i]      = m[i];
      cmb[wv][16 + fq*4+i] = l[i];
    }
  }
  #pragma unroll
  for (int c = 0; c < 8; c++)
    #pragma unroll
    for (int i = 0; i < 4; i++)
      cmb[wv][32 + (fq*4+i)*128 + c*16 + fr] = acc[c][i];
  __syncthreads();
  if (tid < 16){
    float mm = fmaxf(fmaxf(cmb[0][tid], cmb[1][tid]), fmaxf(cmb[2][tid], cmb[3][tid]));
    float ll = 0.f;
    #pragma unroll
    for (int w = 0; w < 4; w++){
      float e = expf(cmb[w][tid] - mm);
      scl[w][tid] = e;
      ll += e * cmb[w][16 + tid];
    }
    pm[blockIdx.x*16 + tid] = mm;
    pl[blockIdx.x*16 + tid] = ll;
  }
  __syncthreads();
  for (int e = tid; e < 2048; e += 256){
    int q = e >> 7;
    float a = scl[0][q]*cmb[0][32+e] + scl[1][q]*cmb[1][32+e]
            + scl[2][q]*cmb[2][32+e] + scl[3][q]*cmb[3][32+e];
    pacc[(size_t)blockIdx.x*2048 + e] = a;
  }
}

// fused: flash partial combine + read-mode mix + hro concat (h from h_h)
__global__ void k_hro_comb(const _Float16* __restrict__ h, const float* __restrict__ pacc,
                           const float* __restrict__ pm, const float* __restrict__ pl,
                           const float* __restrict__ rm0, const float* __restrict__ rm1,
                           const float* __restrict__ rm2, const float* __restrict__ bwm,
                           const float* __restrict__ fwm, _Float16* __restrict__ hro){
  int idx = blockIdx.x*256 + threadIdx.x;   // 256*1536
  int b = idx / 1536, k = idx - b*1536;
  if (k < 1024){
    hro[idx] = h[b*1024 + k];
  } else {
    int r = k - 1024, rh = r >> 7, d = r & 127;
    int row = b*4 + rh, qt = row >> 4, q = row & 15;
    float mm = -3.0e38f;
    #pragma unroll
    for (int kc = 0; kc < 4; kc++) mm = fmaxf(mm, pm[(qt*4+kc)*16 + q]);
    float num = 0.f, den = 0.f;
    #pragma unroll
    for (int kc = 0; kc < 4; kc++){
      float e = expf(pm[(qt*4+kc)*16 + q] - mm);
      den += e * pl[(qt*4+kc)*16 + q];
      num += e * pacc[(size_t)(qt*4+kc)*2048 + q*128 + d];
    }
    float pv = num / den;
    hro[idx] = (_Float16)(rm0[row]*pv + rm1[row]*bwm[d] + rm2[row]*fwm[d]);
  }
}

// ---------------- launcher ----------------

extern "C" void kernel_launch(void* const* d_in, const int* in_sizes, int n_in,
                              void* d_out, int out_size, void* d_ws, size_t ws_size,
                              hipStream_t stream)
{
  const float* x     = (const float*)d_in[0];
  const float* mem   = (const float*)d_in[1];
  const float* usage = (const float*)d_in[2];
  const float* link  = (const float*)d_in[3];
  const float* W_ih  = (const float*)d_in[4];
  // d_in[5] = W_hh: unused (h0 = 0)
  const float* b_ih  = (const float*)d_in[6];
  const float* b_hh  = (const float*)d_in[7];
  const float* W_if  = (const float*)d_in[8];
  const float* b_if  = (const float*)d_in[9];
  const float* W_out = (const float*)d_in[10];
  const float* b_out = (const float*)d_in[11];
  float* out = (float*)d_out;
  float* ws  = (float*)d_ws;

  // fp32 scratch
  float* cm     = ws + 0;         // 128   (zero region: cm,csl,bwm,fwm = 2432)
  float* csl    = ws + 128;       // 2048
  float* bwm    = ws + 2176;      // 128
  float* fwm    = ws + 2304;      // 128
  float* bw     = ws + 2688;      // 2048
  float* fw     = ws + 4736;      // 2048
  float* wg     = ws + 6784;      // 256
  float* ag     = ws + 7040;      // 256
  float* rm0    = ws + 7296;      // 1024
  float* rm1    = ws + 8320;      // 1024
  float* rm2    = ws + 9344;      // 1024
  float* alloc  = ws + 10368;     // 2048
  float* rsl    = ws + 12416;     // 2048
  float* ev     = ws + 14464;     // 32768 (B x 128)
  float* av     = ws + 47232;     // 32768
  float* g      = ws + 80000;     // 1048576 (B x 4096 LSTM gates)
  float* itf    = ws + 1128576;   // 201472 (B x 787)
  float* ww     = ws + 1330048;   // 524288 (B x 2048)
  float* pacc   = ws + 1854336;   // 524288 (256 blocks x 2048)
  float* pm     = ws + 2378624;   // 4096
  float* pl     = ws + 2382720;   // 4096
  // fp16 scratch
  _Float16* wv_h    = (_Float16*)(ws + 2386816);  //  32,768 h
  _Float16* mem_h   = (_Float16*)(ws + 2403200);  // 262,144 h (row-normalized)
  _Float16* memn_h  = (_Float16*)(ws + 2534272);  // 262,144 h (row-normalized)
  _Float16* memnT_h = (_Float16*)(ws + 2665344);  // 262,144 h (transposed raw)
  _Float16* rks_h   = (_Float16*)(ws + 2796416);  // 131,072 h
  _Float16* hro_h   = (_Float16*)(ws + 2861952);  // 393,216 h
  _Float16* cin_h   = (_Float16*)(ws + 3058560);  // 393,216 h
  _Float16* h_h     = (_Float16*)(ws + 3255168);  // 262,144 h
  float* cslp       = ws + 3386240;               // 524,288 (256 x 2048 col partials)
  // total ~3.91M floats = 15.6 MB

  // stage 0: zero atomic accumulators (cm, bwm, fwm; csl zero harmless)
  k_zero<<<10, 256, 0, stream>>>(ws, 2432);

  // stage 1 (merged, MLP-sized): mem colsum+rownorm | link row/col-partial sums | alloc
  k_stage1<<<896, 256, 0, stream>>>(mem, cm, mem_h, usage, alloc, link, rsl, cslp);
  k_cin_csl<<<1568, 256, 0, stream>>>(x, cm, cin_h, cslp, csl);

  // stage 2: LSTM controller (B = W_ih fp32, deferred-cvt)
  gemm_t<float><<<dim3(64,8), 256, 0, stream>>>(cin_h, W_ih, g, 256, 4096, 1536, b_ih, b_hh);
  k_lstm<<<1024, 256, 0, stream>>>(g, h_h);

  // stage 3: interface (B = W_if fp32, deferred-cvt)
  gemm_t<float><<<dim3(13,8), 256, 0, stream>>>(h_h, W_if, itf, 256, 787, 1024, b_if, nullptr);
  k_parse<<<256, 128, 0, stream>>>(itf, wv_h, ev, av, wg, ag, rm0, rm1, rm2, rks_h);

  // stage 4: write weighting (softmax + write-gates fused)
  gemm_t<_Float16><<<dim3(32,8), 256, 0, stream>>>(wv_h, mem_h, ww, 256, 2048, 128, nullptr, nullptr);
  k_softmax_ww<<<256, 256, 0, stream>>>(ww, alloc, wg, ag);

  // stage 5: link-derived read vectors (Salloc reduced in-kernel; tb analytic)
  k_bwfw<<<32, 256, 0, stream>>>(ww, wg, ag, alloc, rsl, csl, bw, fw);

  // stage 6: memory update (update + norms + fp16 emits + transpose + bwm/fwm fused)
  k_memupdate_fused<<<64, 256, 0, stream>>>(ww, ev, av, mem, bw, fw, memn_h, memnT_h, bwm, fwm);

  // stage 7: flash-fused read addressing (sim never materialized)
  k_flash<<<256, 256, 0, stream>>>(rks_h, memn_h, memnT_h, pacc, pm, pl);

  // stage 8: combine + output projection (B = W_out fp32, deferred-cvt)
  k_hro_comb<<<1536, 256, 0, stream>>>(h_h, pacc, pm, pl, rm0, rm1, rm2, bwm, fwm, hro_h);
  gemm_t<float><<<dim3(16,8), 256, 0, stream>>>(hro_h, W_out, out, 256, 1024, 1536, b_out, nullptr);

  (void)in_sizes; (void)n_in; (void)out_size; (void)ws_size;
}